// Round 8
// baseline (160.734 us; speedup 1.0000x reference)
//
#include <hip/hip_runtime.h>
#include <math.h>

#define B_   4
#define S_   4096
#define D_   1024
#define HD_  64

// ---------------- split-K flash constants ----------------
#define CK            8          // k-tiles (of 64 keys) per chunk
#define CHUNKS_PER_B  288        // sum_{qi=0}^{63} (qi/8 + 1)  (partial slots)
#define PAIRS_CHUNKS  144        // sum_{p=0}^{31} ((2p+1)/8 + 1)  (flash blocks/batch)
#define PSTRIDE       68         // floats per row in a partial slot (o[64], m, l, pad)
#define SLOT_F        (64 * PSTRIDE)

typedef float  f32x4  __attribute__((ext_vector_type(4)));
typedef __bf16 bf16x8 __attribute__((ext_vector_type(8)));

static __device__ __forceinline__ unsigned short f2bf(float f) {
    unsigned int u = __float_as_uint(f);
    u += 0x7FFFu + ((u >> 16) & 1u);          // round-to-nearest-even
    return (unsigned short)(u >> 16);
}

// ------------------------------------------------------------------
// Kernel 0: convert wq/wk/wv (fp32 [64][1024]) into wbf (bf16 [192][1024]).
// ------------------------------------------------------------------
__global__ __launch_bounds__(256) void convert_w(
    const float* __restrict__ wq, const float* __restrict__ wk,
    const float* __restrict__ wv, unsigned short* __restrict__ wbf)
{
    const int col = blockIdx.x;            // 0..191
    const int p = col >> 6, h = col & 63;
    const float* src = (p == 0 ? wq : (p == 1 ? wk : wv)) + (size_t)h * D_;
    const int t = threadIdx.x;
    const float4 v = ((const float4*)src)[t];
    ushort4 o;
    o.x = f2bf(v.x); o.y = f2bf(v.y); o.z = f2bf(v.z); o.w = f2bf(v.w);
    *(ushort4*)&wbf[(size_t)col * D_ + 4 * t] = o;
}

// ------------------------------------------------------------------
// Kernel 1: QKV projection via bf16 MFMA (16x16x32), BK=128.
// Unchanged from R7 (measured ~30 us, 4 blocks/CU).
// ------------------------------------------------------------------
__global__ __launch_bounds__(256) void proj_mfma(
    const float* __restrict__ x, const unsigned short* __restrict__ wbf,
    const float* __restrict__ bq, const float* __restrict__ bk,
    const float* __restrict__ bv,
    unsigned short* __restrict__ qbf, unsigned short* __restrict__ kbf,
    unsigned short* __restrict__ vtb)
{
    __shared__ unsigned short xs[32][136];    // 8704 B
    __shared__ unsigned short wsh[96][136];   // 26112 B

    const int t = threadIdx.x;
    const int w = t >> 6, lane = t & 63;
    const int n = lane & 15, g = lane >> 4;
    const int koff = 8 * g;
    const int rt = w & 1, cg = w >> 1;
    const size_t row0 = (size_t)blockIdx.x * 32;
    const int colbase = 96 * blockIdx.y;

    f32x4 acc[3];
#pragma unroll
    for (int i = 0; i < 3; ++i) acc[i] = (f32x4)0.f;

    for (int chunk = 0; chunk < 8; ++chunk) {
        const int d0 = chunk * 128;
        __syncthreads();
#pragma unroll
        for (int i = 0; i < 4; ++i) {
            int e = t + i * 256;              // 0..1023 float4
            int r = e >> 5, c4 = (e & 31) * 4;
            float4 v = *(const float4*)&x[(row0 + r) * D_ + d0 + c4];
            ushort4 o;
            o.x = f2bf(v.x); o.y = f2bf(v.y); o.z = f2bf(v.z); o.w = f2bf(v.w);
            *(ushort4*)&xs[r][c4] = o;
        }
#pragma unroll
        for (int i = 0; i < 6; ++i) {
            int e = t + i * 256;              // 0..1535
            int col = e >> 4, g8 = (e & 15) * 8;
            uint4 v = *(const uint4*)&wbf[(size_t)(colbase + col) * D_ + d0 + g8];
            *(uint4*)&wsh[col][g8] = v;
        }
        __syncthreads();

#pragma unroll
        for (int ks = 0; ks < 4; ++ks) {
            const int k0 = 32 * ks;
            const bf16x8 a = *(const bf16x8*)&xs[16 * rt + n][k0 + koff];
#pragma unroll
            for (int ci = 0; ci < 3; ++ci) {
                const bf16x8 b = *(const bf16x8*)&wsh[48 * cg + 16 * ci + n][k0 + koff];
                acc[ci] = __builtin_amdgcn_mfma_f32_16x16x32_bf16(a, b, acc[ci], 0, 0, 0);
            }
        }
    }

#pragma unroll
    for (int ci = 0; ci < 3; ++ci) {
        const int gct = 6 * blockIdx.y + 3 * cg + ci;
        const int p = gct >> 2, h0 = (gct & 3) * 16;
        const int h = h0 + n;
        const float bb = (p == 0 ? bq : (p == 1 ? bk : bv))[h];
        if (p == 2) {
            const size_t grow0 = row0 + 16 * rt + 4 * g;
            const int bidx = (int)(grow0 >> 12);
            const int s0 = (int)(grow0 & 4095);
            ushort4 u;
            u.x = f2bf(acc[ci][0] + bb); u.y = f2bf(acc[ci][1] + bb);
            u.z = f2bf(acc[ci][2] + bb); u.w = f2bf(acc[ci][3] + bb);
            *(ushort4*)&vtb[((size_t)bidx * HD_ + h) * S_ + s0] = u;
        } else {
            unsigned short* outp = (p == 0 ? qbf : kbf);
            const float scale = (p == 0) ? 0.125f : 1.0f;
#pragma unroll
            for (int r = 0; r < 4; ++r) {
                const size_t grow = row0 + 16 * rt + 4 * g + r;
                outp[grow * HD_ + h] = f2bf((acc[ci][r] + bb) * scale);
            }
        }
    }
}

// ------------------------------------------------------------------
// Kernel 2: split-K causal flash attention, bf16 MFMA, q-PAIRED:
// one 512-thread block = two adjacent q-tiles (2p, 2p+1) sharing K/V
// staging. Waves 0-3 -> tile A (qt=0), waves 4-7 -> tile B (qt=1);
// wave handles q-rows 16*(w&3).. within its tile. Barrier count and
// K/V fetch per unit work are halved vs R5/R7.
// Partial-slot layout per (b, qi, c) is IDENTICAL to before (for even
// qi, ((qi+1)>>3) == (qi>>3) since qi+1 is odd) -> combine unchanged.
// ------------------------------------------------------------------
__global__ __launch_bounds__(512) void flash_splitk(
    const unsigned short* __restrict__ qg, const unsigned short* __restrict__ kg,
    const unsigned short* __restrict__ vt, float* __restrict__ out,
    float* __restrict__ part)
{
    __shared__ unsigned short qsh[128][72];     // 18432 B  Q rows, tiles A+B
    __shared__ unsigned short ksh[64][72];      //  9216 B  K rows
    __shared__ unsigned short vsh[64][72];      //  9216 B  vT[h][key]
    __shared__ unsigned short psh[8][16][72];   // 18432 B  per-wave P[q][key]

    const int t    = threadIdx.x;
    const int w    = t >> 6;         // 0..7
    const int lane = t & 63;
    const int n    = lane & 15;      // MFMA col index
    const int g    = lane >> 4;      // MFMA row group
    const int koff = 8 * g;
    const int qt   = w >> 2;         // 0 = tile A (qi=2p), 1 = tile B (qi=2p+1)
    const int wq   = w & 3;          // q-subtile within the wave's q-tile
    const int b    = blockIdx.y;

    // decode blockIdx.x -> (p, c); chunks per pair = ((2p+1)>>3)+1
    int p = 0, rem = blockIdx.x;
    while (rem >= (((2 * p + 1) >> 3) + 1)) { rem -= ((2 * p + 1) >> 3) + 1; ++p; }
    const int c    = rem;
    const int qiA  = 2 * p;
    const int qi_w = qiA + qt;                   // this wave's q-tile index
    const int kt0  = c * CK;
    const int kt1  = min(qiA + 1, kt0 + CK - 1);
    const int nc   = ((qiA + 1) >> 3) + 1;       // chunk count (same for both tiles)

    // stage Q (once): 128 rows = 1024 uint4, 2 per thread
    {
        const uint4* src = (const uint4*)(qg + ((size_t)b * S_ + (size_t)qiA * 64) * HD_);
#pragma unroll
        for (int i = 0; i < 2; ++i) {
            int e = t + i * 512;                 // 0..1023
            int r = e >> 3, gg = e & 7;
            *(uint4*)&qsh[r][8 * gg] = src[e];
        }
    }

    f32x4 o4[4];
#pragma unroll
    for (int i = 0; i < 4; ++i) o4[i] = (f32x4)0.f;
    float m_r = -INFINITY, l_r = 0.f;

    const int qrow = 64 * qt + 16 * wq;          // wave's first q row in qsh

    for (int kt = kt0; kt <= kt1; ++kt) {
        const size_t kvbase = ((size_t)b * S_ + (size_t)kt * 64) * HD_;
        __syncthreads();                         // prev reads done (covers qsh on iter 0)
        {   // stage K and vT: 512 uint4 each, 1 per thread
            const int r = t >> 3, gg = t & 7;
            *(uint4*)&ksh[r][8 * gg] = *(const uint4*)&kg[kvbase + (size_t)r * HD_ + 8 * gg];
            *(uint4*)&vsh[r][8 * gg] =
                *(const uint4*)&vt[((size_t)b * HD_ + r) * S_ + kt * 64 + 8 * gg];
        }
        __syncthreads();

        if (kt <= qi_w) {                        // A-waves skip kt = 2p+1 (uniform)
            // ---- S^T = K . Q^T : 4 m-tiles (keys) x 16 q ----
            f32x4 sc[4];
#pragma unroll
            for (int mt = 0; mt < 4; ++mt) sc[mt] = (f32x4)0.f;
#pragma unroll
            for (int ks = 0; ks < 2; ++ks) {
                const bf16x8 bq8 = *(const bf16x8*)&qsh[qrow + n][32 * ks + koff];
#pragma unroll
                for (int mt = 0; mt < 4; ++mt) {
                    const bf16x8 ak = *(const bf16x8*)&ksh[16 * mt + n][32 * ks + koff];
                    sc[mt] = __builtin_amdgcn_mfma_f32_16x16x32_bf16(ak, bq8, sc[mt], 0, 0, 0);
                }
            }

            // ---- causal mask (diagonal k-tile only) ----
            if (kt == qi_w) {
                const int qloc = 16 * wq + n;
#pragma unroll
                for (int mt = 0; mt < 4; ++mt)
#pragma unroll
                    for (int r = 0; r < 4; ++r) {
                        const int kloc = 16 * mt + 4 * g + r;
                        if (kloc > qloc) sc[mt][r] = -INFINITY;
                    }
            }

            // ---- online softmax per column q ----
            float mx = -INFINITY;
#pragma unroll
            for (int mt = 0; mt < 4; ++mt)
#pragma unroll
                for (int r = 0; r < 4; ++r) mx = fmaxf(mx, sc[mt][r]);
            mx = fmaxf(mx, __shfl_xor(mx, 16));
            mx = fmaxf(mx, __shfl_xor(mx, 32));

            const float m_new = fmaxf(m_r, mx);
            const float alpha = __expf(m_r - m_new);
            float psum = 0.f;
#pragma unroll
            for (int mt = 0; mt < 4; ++mt)
#pragma unroll
                for (int r = 0; r < 4; ++r) {
                    const float pe = __expf(sc[mt][r] - m_new);
                    sc[mt][r] = pe;
                    psum += pe;
                }
            psum += __shfl_xor(psum, 16);
            psum += __shfl_xor(psum, 32);
            l_r = l_r * alpha + psum;
            m_r = m_new;

            // rescale O rows (row q = 4g+r needs alpha of column 4g+r)
#pragma unroll
            for (int r = 0; r < 4; ++r) {
                const float ar = __shfl(alpha, 4 * g + r);
#pragma unroll
                for (int ht = 0; ht < 4; ++ht) o4[ht][r] *= ar;
            }

            // ---- pack P^T -> per-wave LDS p[q][key] ----
#pragma unroll
            for (int mt = 0; mt < 4; ++mt) {
                ushort4 u;
                u.x = f2bf(sc[mt][0]); u.y = f2bf(sc[mt][1]);
                u.z = f2bf(sc[mt][2]); u.w = f2bf(sc[mt][3]);
                *(ushort4*)&psh[w][n][16 * mt + 4 * g] = u;
            }
            // same-wave RAW on LDS: compiler inserts lgkmcnt wait; no barrier needed

            // ---- O += P . V ----
#pragma unroll
            for (int ks = 0; ks < 2; ++ks) {
                const bf16x8 ap = *(const bf16x8*)&psh[w][n][32 * ks + koff];
#pragma unroll
                for (int ht = 0; ht < 4; ++ht) {
                    const bf16x8 bv8 = *(const bf16x8*)&vsh[16 * ht + n][32 * ks + koff];
                    o4[ht] = __builtin_amdgcn_mfma_f32_16x16x32_bf16(ap, bv8, o4[ht], 0, 0, 0);
                }
            }
        }
    }

    const size_t qbase = ((size_t)b * S_ + (size_t)qi_w * 64) * HD_;
    if (nc == 1) {
#pragma unroll
        for (int r = 0; r < 4; ++r) {
            const float lr = __shfl(l_r, 4 * g + r);
            const float inv = 1.f / lr;
            const size_t ob = qbase + (size_t)(16 * wq + 4 * g + r) * HD_;
#pragma unroll
            for (int ht = 0; ht < 4; ++ht)
                out[ob + 16 * ht + n] = o4[ht][r] * inv;
        }
    } else {
        int cum = 0;
        for (int j = 0; j < qi_w; ++j) cum += (j >> 3) + 1;
        const size_t sb = ((size_t)b * CHUNKS_PER_B + cum + c) * SLOT_F;
#pragma unroll
        for (int r = 0; r < 4; ++r) {
            const size_t pb = sb + (size_t)(16 * wq + 4 * g + r) * PSTRIDE;
#pragma unroll
            for (int ht = 0; ht < 4; ++ht)
                part[pb + 16 * ht + n] = o4[ht][r];
        }
        if (g == 0) {
            part[sb + (size_t)(16 * wq + n) * PSTRIDE + 64] = m_r;
            part[sb + (size_t)(16 * wq + n) * PSTRIDE + 65] = l_r;
        }
    }
}

// ------------------------------------------------------------------
// Kernel 3: merge partials for qi >= CK.  grid = (56, B). Unchanged.
// ------------------------------------------------------------------
__global__ __launch_bounds__(256) void combine(
    const float* __restrict__ part, float* __restrict__ out)
{
    const int t  = threadIdx.x;
    const int qr = t >> 2, tc = t & 3;
    const int qi = blockIdx.x + CK;          // 8..63
    const int b  = blockIdx.y;
    const int nc = (qi >> 3) + 1;

    int cum = 0;
    for (int j = 0; j < qi; ++j) cum += (j >> 3) + 1;
    const size_t base0 = ((size_t)b * CHUNKS_PER_B + cum) * SLOT_F;

    float M = -INFINITY;
    for (int c0 = 0; c0 < nc; ++c0)
        M = fmaxf(M, part[base0 + (size_t)c0 * SLOT_F + qr * PSTRIDE + 64]);

    float L = 0.f;
    float o[16];
#pragma unroll
    for (int j = 0; j < 16; ++j) o[j] = 0.f;

    for (int c0 = 0; c0 < nc; ++c0) {
        const size_t sb = base0 + (size_t)c0 * SLOT_F + qr * PSTRIDE;
        const float m_c = part[sb + 64];
        const float l_c = part[sb + 65];
        const float w = __expf(m_c - M);
        L += w * l_c;
#pragma unroll
        for (int j = 0; j < 4; ++j) {
            const float4 ov = *(const float4*)&part[sb + tc * 16 + 4 * j];
            o[4 * j + 0] += w * ov.x; o[4 * j + 1] += w * ov.y;
            o[4 * j + 2] += w * ov.z; o[4 * j + 3] += w * ov.w;
        }
    }

    const float inv = 1.f / L;
    const size_t qbase = ((size_t)b * S_ + (size_t)qi * 64) * HD_;
#pragma unroll
    for (int j = 0; j < 4; ++j) {
        float4 r;
        r.x = o[4 * j + 0] * inv; r.y = o[4 * j + 1] * inv;
        r.z = o[4 * j + 2] * inv; r.w = o[4 * j + 3] * inv;
        *(float4*)&out[qbase + 16 * t + 4 * j] = r;
    }
}

// ------------------------------------------------------------------
extern "C" void kernel_launch(void* const* d_in, const int* in_sizes, int n_in,
                              void* d_out, int out_size, void* d_ws, size_t ws_size,
                              hipStream_t stream)
{
    const float* x  = (const float*)d_in[0];
    const float* wq = (const float*)d_in[1];
    const float* bq = (const float*)d_in[2];
    const float* wk = (const float*)d_in[3];
    const float* bk = (const float*)d_in[4];
    const float* wv = (const float*)d_in[5];
    const float* bv = (const float*)d_in[6];
    float* outp = (float*)d_out;

    // ws layout: qbf | kbf | vt (bf16, n each) | wbf (bf16) | part (fp32)
    const size_t n = (size_t)B_ * S_ * HD_;        // 1048576
    unsigned short* qbf = (unsigned short*)d_ws;
    unsigned short* kbf = qbf + n;
    unsigned short* vtb = kbf + n;
    unsigned short* wbf = vtb + n;                 // 192*1024 bf16
    float* part = (float*)(wbf + (size_t)192 * D_);

    convert_w<<<dim3(192), 256, 0, stream>>>(wq, wk, wv, wbf);
    proj_mfma<<<dim3(B_ * S_ / 32, 2), 256, 0, stream>>>(
        x, wbf, bq, bk, bv, qbf, kbf, vtb);
    flash_splitk<<<dim3(PAIRS_CHUNKS, B_), 512, 0, stream>>>(qbf, kbf, vtb, outp, part);
    combine<<<dim3(S_ / 64 - CK, B_), 256, 0, stream>>>(part, outp);
}

// Round 9
// 154.865 us; speedup vs baseline: 1.0379x; 1.0379x over previous
//
#include <hip/hip_runtime.h>
#include <math.h>

#define B_   4
#define S_   4096
#define D_   1024
#define HD_  64

// ---------------- split-K flash constants ----------------
#define CK            8          // k-tiles (of 64 keys) per chunk
#define CHUNKS_PER_B  288        // sum_{qi=0}^{63} (qi/8 + 1)  (partial slots)
#define FULL_CHUNKS   224        // sum_{qi=0}^{63} (qi/8)      (8-iter chunks/batch)
#define PSTRIDE       68         // floats per row in a partial slot (o[64], m, l, pad)
#define SLOT_F        (64 * PSTRIDE)

typedef float  f32x4  __attribute__((ext_vector_type(4)));
typedef __bf16 bf16x8 __attribute__((ext_vector_type(8)));

static __device__ __forceinline__ unsigned short f2bf(float f) {
    unsigned int u = __float_as_uint(f);
    u += 0x7FFFu + ((u >> 16) & 1u);          // round-to-nearest-even
    return (unsigned short)(u >> 16);
}

// slot index of (qi, c) within a batch: qi + sum_{j<qi}(j>>3) + c
static __device__ __forceinline__ int chunk_slot(int qi, int c) {
    const int a = qi >> 3, r = qi & 7;
    return qi + 4 * a * (a - 1) + a * r + c;
}

// ------------------------------------------------------------------
// Kernel 0: convert wq/wk/wv (fp32 [64][1024]) into wbf (bf16 [192][1024]).
// ------------------------------------------------------------------
__global__ __launch_bounds__(256) void convert_w(
    const float* __restrict__ wq, const float* __restrict__ wk,
    const float* __restrict__ wv, unsigned short* __restrict__ wbf)
{
    const int col = blockIdx.x;            // 0..191
    const int p = col >> 6, h = col & 63;
    const float* src = (p == 0 ? wq : (p == 1 ? wk : wv)) + (size_t)h * D_;
    const int t = threadIdx.x;
    const float4 v = ((const float4*)src)[t];
    ushort4 o;
    o.x = f2bf(v.x); o.y = f2bf(v.y); o.z = f2bf(v.z); o.w = f2bf(v.w);
    *(ushort4*)&wbf[(size_t)col * D_ + 4 * t] = o;
}

// ------------------------------------------------------------------
// Kernel 1: QKV projection via bf16 MFMA (16x16x32), BK=128.
// Unchanged from R7 (measured ~30 us, 4 blocks/CU).
// ------------------------------------------------------------------
__global__ __launch_bounds__(256) void proj_mfma(
    const float* __restrict__ x, const unsigned short* __restrict__ wbf,
    const float* __restrict__ bq, const float* __restrict__ bk,
    const float* __restrict__ bv,
    unsigned short* __restrict__ qbf, unsigned short* __restrict__ kbf,
    unsigned short* __restrict__ vtb)
{
    __shared__ unsigned short xs[32][136];    // 8704 B
    __shared__ unsigned short wsh[96][136];   // 26112 B

    const int t = threadIdx.x;
    const int w = t >> 6, lane = t & 63;
    const int n = lane & 15, g = lane >> 4;
    const int koff = 8 * g;
    const int rt = w & 1, cg = w >> 1;
    const size_t row0 = (size_t)blockIdx.x * 32;
    const int colbase = 96 * blockIdx.y;

    f32x4 acc[3];
#pragma unroll
    for (int i = 0; i < 3; ++i) acc[i] = (f32x4)0.f;

    for (int chunk = 0; chunk < 8; ++chunk) {
        const int d0 = chunk * 128;
        __syncthreads();
#pragma unroll
        for (int i = 0; i < 4; ++i) {
            int e = t + i * 256;              // 0..1023 float4
            int r = e >> 5, c4 = (e & 31) * 4;
            float4 v = *(const float4*)&x[(row0 + r) * D_ + d0 + c4];
            ushort4 o;
            o.x = f2bf(v.x); o.y = f2bf(v.y); o.z = f2bf(v.z); o.w = f2bf(v.w);
            *(ushort4*)&xs[r][c4] = o;
        }
#pragma unroll
        for (int i = 0; i < 6; ++i) {
            int e = t + i * 256;              // 0..1535
            int col = e >> 4, g8 = (e & 15) * 8;
            uint4 v = *(const uint4*)&wbf[(size_t)(colbase + col) * D_ + d0 + g8];
            *(uint4*)&wsh[col][g8] = v;
        }
        __syncthreads();

#pragma unroll
        for (int ks = 0; ks < 4; ++ks) {
            const int k0 = 32 * ks;
            const bf16x8 a = *(const bf16x8*)&xs[16 * rt + n][k0 + koff];
#pragma unroll
            for (int ci = 0; ci < 3; ++ci) {
                const bf16x8 b = *(const bf16x8*)&wsh[48 * cg + 16 * ci + n][k0 + koff];
                acc[ci] = __builtin_amdgcn_mfma_f32_16x16x32_bf16(a, b, acc[ci], 0, 0, 0);
            }
        }
    }

#pragma unroll
    for (int ci = 0; ci < 3; ++ci) {
        const int gct = 6 * blockIdx.y + 3 * cg + ci;
        const int p = gct >> 2, h0 = (gct & 3) * 16;
        const int h = h0 + n;
        const float bb = (p == 0 ? bq : (p == 1 ? bk : bv))[h];
        if (p == 2) {
            const size_t grow0 = row0 + 16 * rt + 4 * g;
            const int bidx = (int)(grow0 >> 12);
            const int s0 = (int)(grow0 & 4095);
            ushort4 u;
            u.x = f2bf(acc[ci][0] + bb); u.y = f2bf(acc[ci][1] + bb);
            u.z = f2bf(acc[ci][2] + bb); u.w = f2bf(acc[ci][3] + bb);
            *(ushort4*)&vtb[((size_t)bidx * HD_ + h) * S_ + s0] = u;
        } else {
            unsigned short* outp = (p == 0 ? qbf : kbf);
            const float scale = (p == 0) ? 0.125f : 1.0f;
#pragma unroll
            for (int r = 0; r < 4; ++r) {
                const size_t grow = row0 + 16 * rt + 4 * g + r;
                outp[grow * HD_ + h] = f2bf((acc[ci][r] + bb) * scale);
            }
        }
    }
}

// ------------------------------------------------------------------
// Kernel 2: split-K causal flash attention, bf16 MFMA (R7 structure,
// 256 thr, 4 blocks/CU) with two changes:
//  (a) PV computed as O^T = vT . P^T (operand swap; identical LDS
//      reads since A/B fragment maps coincide). O cols = q = n, so
//      alpha/l are in-lane (no shfl) and stores are float4.
//  (b) 1-D grid (1152) in work-descending order: full 8-iter chunks
//      dispatched first (idx<896), partial chunks last (tail fill).
// ------------------------------------------------------------------
__global__ __launch_bounds__(256) void flash_splitk(
    const unsigned short* __restrict__ qg, const unsigned short* __restrict__ kg,
    const unsigned short* __restrict__ vt, float* __restrict__ out,
    float* __restrict__ part)
{
    __shared__ unsigned short qsh[64][72];      // 9216 B  Q rows (pre-scaled)
    __shared__ unsigned short ksh[64][72];      // 9216 B  K rows
    __shared__ unsigned short vsh[64][72];      // 9216 B  vT[h][key]
    __shared__ unsigned short psh[4][16][72];   // 9216 B  per-wave P[q][key]

    const int t    = threadIdx.x;
    const int w    = t >> 6;
    const int lane = t & 63;
    const int n    = lane & 15;      // MFMA col index
    const int g    = lane >> 4;      // MFMA row group
    const int koff = 8 * g;

    // decode blockIdx.x -> (b, qi, c), full chunks first
    int b, qi, c;
    {
        const int idx = blockIdx.x;
        if (idx < B_ * FULL_CHUNKS) {          // full 8-iteration chunks
            b = idx / FULL_CHUNKS;
            int rem = idx - b * FULL_CHUNKS;
            qi = 8;
            while (rem >= (qi >> 3)) { rem -= (qi >> 3); ++qi; }
            c = rem;
        } else {                               // last (partial) chunk of each qi
            const int r2 = idx - B_ * FULL_CHUNKS;
            b = r2 >> 6;
            qi = r2 & 63;
            c = qi >> 3;
        }
    }
    const int kt0 = c * CK;
    const int kt1 = min(qi, kt0 + CK - 1);
    const int nc  = (qi >> 3) + 1;

    const size_t qtile = ((size_t)b * S_ + (size_t)qi * 64) * HD_;

    // stage Q (once): 2 uint4/thread
    {
        const uint4* src = (const uint4*)(qg + qtile);
#pragma unroll
        for (int i = 0; i < 2; ++i) {
            int e = t + i * 256;                // 0..511
            int r = e >> 3, gg = e & 7;
            *(uint4*)&qsh[r][8 * gg] = src[e];
        }
    }

    f32x4 o4[4];                                 // O^T[h=16ht+4g+r][q=n]
#pragma unroll
    for (int i = 0; i < 4; ++i) o4[i] = (f32x4)0.f;
    float m_r = -INFINITY, l_r = 0.f;            // state of q = 16w+n

    for (int kt = kt0; kt <= kt1; ++kt) {
        const size_t kvbase = ((size_t)b * S_ + (size_t)kt * 64) * HD_;
        __syncthreads();                        // prev reads done (covers qsh on iter 0)
        {
            const uint4* ksrc = (const uint4*)(kg + kvbase);
#pragma unroll
            for (int i = 0; i < 2; ++i) {
                int e = t + i * 256;
                int r = e >> 3, gg = e & 7;
                *(uint4*)&ksh[r][8 * gg] = ksrc[e];
            }
#pragma unroll
            for (int i = 0; i < 2; ++i) {
                int e = t + i * 256;
                int h = e >> 3, gg = e & 7;     // vt[b][h][kt*64 + 8gg..]
                *(uint4*)&vsh[h][8 * gg] =
                    *(const uint4*)&vt[((size_t)b * HD_ + h) * S_ + kt * 64 + 8 * gg];
            }
        }
        __syncthreads();

        // ---- S^T = K . Q^T : 4 m-tiles (keys) x 16 q (col = q = n) ----
        f32x4 sc[4];
#pragma unroll
        for (int mt = 0; mt < 4; ++mt) sc[mt] = (f32x4)0.f;
#pragma unroll
        for (int ks = 0; ks < 2; ++ks) {
            const bf16x8 bq8 = *(const bf16x8*)&qsh[16 * w + n][32 * ks + koff];
#pragma unroll
            for (int mt = 0; mt < 4; ++mt) {
                const bf16x8 ak = *(const bf16x8*)&ksh[16 * mt + n][32 * ks + koff];
                sc[mt] = __builtin_amdgcn_mfma_f32_16x16x32_bf16(ak, bq8, sc[mt], 0, 0, 0);
            }
        }

        // ---- causal mask (diagonal k-tile only) ----
        if (kt == qi) {
            const int qloc = 16 * w + n;
#pragma unroll
            for (int mt = 0; mt < 4; ++mt)
#pragma unroll
                for (int r = 0; r < 4; ++r) {
                    const int kloc = 16 * mt + 4 * g + r;
                    if (kloc > qloc) sc[mt][r] = -INFINITY;
                }
        }

        // ---- online softmax per column q (reduce across g via shfl) ----
        float mx = -INFINITY;
#pragma unroll
        for (int mt = 0; mt < 4; ++mt)
#pragma unroll
            for (int r = 0; r < 4; ++r) mx = fmaxf(mx, sc[mt][r]);
        mx = fmaxf(mx, __shfl_xor(mx, 16));
        mx = fmaxf(mx, __shfl_xor(mx, 32));

        const float m_new = fmaxf(m_r, mx);
        const float alpha = __expf(m_r - m_new);
        float psum = 0.f;
#pragma unroll
        for (int mt = 0; mt < 4; ++mt)
#pragma unroll
            for (int r = 0; r < 4; ++r) {
                const float pe = __expf(sc[mt][r] - m_new);
                sc[mt][r] = pe;
                psum += pe;
            }
        psum += __shfl_xor(psum, 16);
        psum += __shfl_xor(psum, 32);
        l_r = l_r * alpha + psum;
        m_r = m_new;

        // rescale O (all regs have col q = n -> alpha is in-lane)
#pragma unroll
        for (int ht = 0; ht < 4; ++ht)
#pragma unroll
            for (int r = 0; r < 4; ++r) o4[ht][r] *= alpha;

        // ---- pack P^T -> per-wave LDS p[q][key] ----
#pragma unroll
        for (int mt = 0; mt < 4; ++mt) {
            ushort4 u;
            u.x = f2bf(sc[mt][0]); u.y = f2bf(sc[mt][1]);
            u.z = f2bf(sc[mt][2]); u.w = f2bf(sc[mt][3]);
            *(ushort4*)&psh[w][n][16 * mt + 4 * g] = u;
        }
        // same-wave RAW on LDS: compiler inserts lgkmcnt wait; no barrier needed

        // ---- O^T += vT . P^T  (A = vT rows, B = P^T; same LDS reads) ----
#pragma unroll
        for (int ks = 0; ks < 2; ++ks) {
            const bf16x8 ap = *(const bf16x8*)&psh[w][n][32 * ks + koff];
#pragma unroll
            for (int ht = 0; ht < 4; ++ht) {
                const bf16x8 av = *(const bf16x8*)&vsh[16 * ht + n][32 * ks + koff];
                o4[ht] = __builtin_amdgcn_mfma_f32_16x16x32_bf16(av, ap, o4[ht], 0, 0, 0);
            }
        }
    }

    const size_t qbase = ((size_t)b * S_ + (size_t)qi * 64) * HD_;
    if (nc == 1) {
        const float inv = 1.f / l_r;             // in-lane (q = 16w+n)
        const size_t ob = qbase + (size_t)(16 * w + n) * HD_;
#pragma unroll
        for (int ht = 0; ht < 4; ++ht) {
            float4 rv;
            rv.x = o4[ht][0] * inv; rv.y = o4[ht][1] * inv;
            rv.z = o4[ht][2] * inv; rv.w = o4[ht][3] * inv;
            *(float4*)&out[ob + 16 * ht + 4 * g] = rv;
        }
    } else {
        const size_t sb = ((size_t)b * CHUNKS_PER_B + chunk_slot(qi, c)) * SLOT_F;
        const size_t pb = sb + (size_t)(16 * w + n) * PSTRIDE;
#pragma unroll
        for (int ht = 0; ht < 4; ++ht) {
            float4 rv;
            rv.x = o4[ht][0]; rv.y = o4[ht][1];
            rv.z = o4[ht][2]; rv.w = o4[ht][3];
            *(float4*)&part[pb + 16 * ht + 4 * g] = rv;
        }
        if (g == 0) {
            part[pb + 64] = m_r;
            part[pb + 65] = l_r;
        }
    }
}

// ------------------------------------------------------------------
// Kernel 3: merge partials for qi >= CK.  grid = (56, B).
// ------------------------------------------------------------------
__global__ __launch_bounds__(256) void combine(
    const float* __restrict__ part, float* __restrict__ out)
{
    const int t  = threadIdx.x;
    const int qr = t >> 2, tc = t & 3;
    const int qi = blockIdx.x + CK;          // 8..63
    const int b  = blockIdx.y;
    const int nc = (qi >> 3) + 1;

    const size_t base0 = ((size_t)b * CHUNKS_PER_B + chunk_slot(qi, 0)) * SLOT_F;

    float M = -INFINITY;
    for (int c0 = 0; c0 < nc; ++c0)
        M = fmaxf(M, part[base0 + (size_t)c0 * SLOT_F + qr * PSTRIDE + 64]);

    float L = 0.f;
    float o[16];
#pragma unroll
    for (int j = 0; j < 16; ++j) o[j] = 0.f;

    for (int c0 = 0; c0 < nc; ++c0) {
        const size_t sb = base0 + (size_t)c0 * SLOT_F + qr * PSTRIDE;
        const float m_c = part[sb + 64];
        const float l_c = part[sb + 65];
        const float w = __expf(m_c - M);
        L += w * l_c;
#pragma unroll
        for (int j = 0; j < 4; ++j) {
            const float4 ov = *(const float4*)&part[sb + tc * 16 + 4 * j];
            o[4 * j + 0] += w * ov.x; o[4 * j + 1] += w * ov.y;
            o[4 * j + 2] += w * ov.z; o[4 * j + 3] += w * ov.w;
        }
    }

    const float inv = 1.f / L;
    const size_t qbase = ((size_t)b * S_ + (size_t)qi * 64) * HD_;
#pragma unroll
    for (int j = 0; j < 4; ++j) {
        float4 r;
        r.x = o[4 * j + 0] * inv; r.y = o[4 * j + 1] * inv;
        r.z = o[4 * j + 2] * inv; r.w = o[4 * j + 3] * inv;
        *(float4*)&out[qbase + 16 * t + 4 * j] = r;
    }
}

// ------------------------------------------------------------------
extern "C" void kernel_launch(void* const* d_in, const int* in_sizes, int n_in,
                              void* d_out, int out_size, void* d_ws, size_t ws_size,
                              hipStream_t stream)
{
    const float* x  = (const float*)d_in[0];
    const float* wq = (const float*)d_in[1];
    const float* bq = (const float*)d_in[2];
    const float* wk = (const float*)d_in[3];
    const float* bk = (const float*)d_in[4];
    const float* wv = (const float*)d_in[5];
    const float* bv = (const float*)d_in[6];
    float* outp = (float*)d_out;

    // ws layout: qbf | kbf | vt (bf16, n each) | wbf (bf16) | part (fp32)
    const size_t n = (size_t)B_ * S_ * HD_;        // 1048576
    unsigned short* qbf = (unsigned short*)d_ws;
    unsigned short* kbf = qbf + n;
    unsigned short* vtb = kbf + n;
    unsigned short* wbf = vtb + n;                 // 192*1024 bf16
    float* part = (float*)(wbf + (size_t)192 * D_);

    convert_w<<<dim3(192), 256, 0, stream>>>(wq, wk, wv, wbf);
    proj_mfma<<<dim3(B_ * S_ / 32, 2), 256, 0, stream>>>(
        x, wbf, bq, bk, bv, qbf, kbf, vtb);
    flash_splitk<<<dim3(B_ * CHUNKS_PER_B), 256, 0, stream>>>(qbf, kbf, vtb, outp, part);
    combine<<<dim3(S_ / 64 - CK, B_), 256, 0, stream>>>(part, outp);
}